// Round 3
// baseline (274.519 us; speedup 1.0000x reference)
//
#include <hip/hip_runtime.h>

// region_pooling via scatter + dense GEMM.
// F: [B=8, HW=4096, C=1024] fp32 (H=W=64); pc: [B, M=32, P=512, 2]
// out[b,m,c] = sum_hw W[b][hw][m] * F[b][hw][c], W = scattered bilinear
// weights pre-scaled by 1/P.

#define NB 8
#define NM 32
#define NP 512
#define NC 1024
#define NH 64
#define NHW 4096

#define KC   64                   // hw per k-chunk
#define NKC  (NHW / KC)           // 64
#define CT   256                  // channels per block (1 per thread)
#define NCT  (NC / CT)            // 4

// ---- Phase 1: scatter bilinear weights into W[b][hw][m] (pre-zeroed) ----
__global__ __launch_bounds__(256) void scatter_w(
    const float* __restrict__ pc, float* __restrict__ W)
{
    int idx = blockIdx.x * 256 + threadIdx.x;   // [0, B*M*P)
    int bm  = idx >> 9;                         // b*NM + m
    int m   = bm & (NM - 1);
    int b   = bm >> 5;

    float2 c = ((const float2*)pc)[idx];
    float y = c.x * 63.0f;
    float x = c.y * 63.0f;
    float x0f = floorf(x), y0f = floorf(y);
    float wx = x - x0f, wy = y - y0f;
    int ix0 = min(max((int)x0f, 0), 63);
    int ix1 = min(ix0 + 1, 63);
    int iy0 = min(max((int)y0f, 0), 63);
    int iy1 = min(iy0 + 1, 63);
    float wx1 = 1.0f - wx, wy1 = 1.0f - wy;
    const float s = 1.0f / (float)NP;           // fold the mean here

    float* Wb = W + (size_t)b * (NHW * NM) + m;
    atomicAdd(Wb + ((iy0 * NH + ix0) * NM), wx1 * wy1 * s);
    atomicAdd(Wb + ((iy0 * NH + ix1) * NM), wx  * wy1 * s);
    atomicAdd(Wb + ((iy1 * NH + ix0) * NM), wx1 * wy  * s);
    atomicAdd(Wb + ((iy1 * NH + ix1) * NM), wx  * wy  * s);
}

// ---- Phase 2: Out[b][m][c] += sum_hw W[b][hw][m] * F[b][hw][c] ----
// 2048 blocks (8/CU). W chunk staged in LDS (8 KB), broadcast ds_read_b128
// in the inner loop; one coalesced F float per thread per k-step.
__global__ __launch_bounds__(256, 8) void wgemm(
    const float* __restrict__ W, const float* __restrict__ F,
    float* __restrict__ out)
{
    __shared__ float4 sW[KC * NM / 4];          // 512 float4 = 8 KB

    const int kc  = blockIdx.x;                 // 64 k-chunks
    const int ct  = blockIdx.y;                 // 4 c-tiles
    const int b   = blockIdx.z;
    const int tid = threadIdx.x;
    const int c   = ct * CT + tid;
    const int hw0 = kc * KC;

    // stage W[hw0:hw0+KC][0:32] -> LDS (2048 floats, 2 float4/thread)
    const float4* Wg = (const float4*)(W + ((size_t)b * NHW + hw0) * NM);
    sW[tid]       = Wg[tid];
    sW[tid + 256] = Wg[tid + 256];
    __syncthreads();

    const float* Fb = F + ((size_t)b * NHW + hw0) * NC + c;

    float acc[NM];
#pragma unroll
    for (int m = 0; m < NM; ++m) acc[m] = 0.0f;

#pragma unroll 4
    for (int i = 0; i < KC; ++i) {
        float f = Fb[(size_t)i * NC];
        const float4* w4 = sW + i * (NM / 4);
#pragma unroll
        for (int mq = 0; mq < NM / 4; ++mq) {
            float4 w = w4[mq];
            acc[mq * 4 + 0] = fmaf(w.x, f, acc[mq * 4 + 0]);
            acc[mq * 4 + 1] = fmaf(w.y, f, acc[mq * 4 + 1]);
            acc[mq * 4 + 2] = fmaf(w.z, f, acc[mq * 4 + 2]);
            acc[mq * 4 + 3] = fmaf(w.w, f, acc[mq * 4 + 3]);
        }
    }

    float* ob = out + (size_t)b * (NM * NC) + c;
#pragma unroll
    for (int m = 0; m < NM; ++m)
        atomicAdd(ob + (size_t)m * NC, acc[m]);
}

// ---- Fallback (ws too small): direct gather ----
__global__ __launch_bounds__(256) void region_pool_direct(
    const float* __restrict__ fm, const float* __restrict__ pc,
    float* __restrict__ out)
{
    __shared__ int4   sIdx[NP];
    __shared__ float4 sWt[NP];
    const int bid = blockIdx.x;
    const int b   = bid >> 5;
    const int tid = threadIdx.x;
    const float2* pc2 = (const float2*)(pc + (size_t)bid * NP * 2);
    for (int p = tid; p < NP; p += 256) {
        float2 c = pc2[p];
        float y = c.x * 63.0f, x = c.y * 63.0f;
        float x0f = floorf(x), y0f = floorf(y);
        float wx = x - x0f, wy = y - y0f;
        int ix0 = min(max((int)x0f, 0), 63);
        int ix1 = min(ix0 + 1, 63);
        int iy0 = min(max((int)y0f, 0), 63);
        int iy1 = min(iy0 + 1, 63);
        sIdx[p] = make_int4((iy0 * NH + ix0) << 10, (iy0 * NH + ix1) << 10,
                            (iy1 * NH + ix0) << 10, (iy1 * NH + ix1) << 10);
        float wx1 = 1.0f - wx, wy1 = 1.0f - wy;
        sWt[p] = make_float4(wx1 * wy1, wx * wy1, wx1 * wy, wx * wy);
    }
    __syncthreads();
    const float* Fb = fm + (size_t)b * (NHW * NC) + tid * 4;
    float4 acc = make_float4(0.f, 0.f, 0.f, 0.f);
#pragma unroll 4
    for (int p = 0; p < NP; ++p) {
        int4 off = sIdx[p]; float4 w = sWt[p];
        float4 f00 = *(const float4*)(Fb + off.x);
        float4 f01 = *(const float4*)(Fb + off.y);
        float4 f10 = *(const float4*)(Fb + off.z);
        float4 f11 = *(const float4*)(Fb + off.w);
        acc.x = fmaf(w.x, f00.x, fmaf(w.y, f01.x, fmaf(w.z, f10.x, fmaf(w.w, f11.x, acc.x))));
        acc.y = fmaf(w.x, f00.y, fmaf(w.y, f01.y, fmaf(w.z, f10.y, fmaf(w.w, f11.y, acc.y))));
        acc.z = fmaf(w.x, f00.z, fmaf(w.y, f01.z, fmaf(w.z, f10.z, fmaf(w.w, f11.z, acc.z))));
        acc.w = fmaf(w.x, f00.w, fmaf(w.y, f01.w, fmaf(w.z, f10.w, fmaf(w.w, f11.w, acc.w))));
    }
    const float inv = 1.0f / (float)NP;
    ((float4*)(out + (size_t)bid * NC))[tid] =
        make_float4(acc.x * inv, acc.y * inv, acc.z * inv, acc.w * inv);
}

extern "C" void kernel_launch(void* const* d_in, const int* in_sizes, int n_in,
                              void* d_out, int out_size, void* d_ws, size_t ws_size,
                              hipStream_t stream) {
    const float* fm = (const float*)d_in[0];   // [8, 4096, 1024]
    const float* pc = (const float*)d_in[1];   // [8, 32, 512, 2]
    float* out = (float*)d_out;                // [8, 32, 1, 1024]

    const size_t wbytes = (size_t)NB * NHW * NM * sizeof(float);  // 4 MB
    if (ws_size >= wbytes) {
        float* W = (float*)d_ws;
        hipMemsetAsync(W, 0, wbytes, stream);
        hipMemsetAsync(out, 0, (size_t)out_size * sizeof(float), stream);
        scatter_w<<<(NB * NM * NP) / 256, 256, 0, stream>>>(pc, W);
        dim3 grid(NKC, NCT, NB);
        wgemm<<<grid, CT, 0, stream>>>(W, fm, out);
    } else {
        region_pool_direct<<<NB * NM, 256, 0, stream>>>(fm, pc, out);
    }
}

// Round 4
// 233.054 us; speedup vs baseline: 1.1779x; 1.1779x over previous
//
#include <hip/hip_runtime.h>

// region_pooling via scatter + dense GEMM + split-k partials (no atomics on out).
// F: [B=8, HW=4096, C=1024] fp32 (H=W=64); pc: [B, M=32, P=512, 2]
// out[b,m,c] = sum_hw W[b][hw][m] * F[b][hw][c]; W = scattered bilinear
// weights pre-scaled by 1/P.

#define NB 8
#define NM 32
#define NP 512
#define NC 1024
#define NH 64
#define NHW 4096

#define KC   256                  // hw per k-chunk
#define NKC  (NHW / KC)           // 16 k-chunks
#define CT   256                  // channels per block (1 per thread)
#define NCT  (NC / CT)            // 4
#define PF   8                    // F prefetch depth

// ---- Phase 1: scatter bilinear weights into W[b][hw][m] (pre-zeroed) ----
__global__ __launch_bounds__(256) void scatter_w(
    const float* __restrict__ pc, float* __restrict__ W)
{
    int idx = blockIdx.x * 256 + threadIdx.x;   // [0, B*M*P)
    int bm  = idx >> 9;                         // b*NM + m
    int m   = bm & (NM - 1);
    int b   = bm >> 5;

    float2 c = ((const float2*)pc)[idx];
    float y = c.x * 63.0f;
    float x = c.y * 63.0f;
    float x0f = floorf(x), y0f = floorf(y);
    float wx = x - x0f, wy = y - y0f;
    int ix0 = min(max((int)x0f, 0), 63);
    int ix1 = min(ix0 + 1, 63);
    int iy0 = min(max((int)y0f, 0), 63);
    int iy1 = min(iy0 + 1, 63);
    float wx1 = 1.0f - wx, wy1 = 1.0f - wy;
    const float s = 1.0f / (float)NP;           // fold the mean here

    float* Wb = W + (size_t)b * (NHW * NM) + m;
    atomicAdd(Wb + ((iy0 * NH + ix0) * NM), wx1 * wy1 * s);
    atomicAdd(Wb + ((iy0 * NH + ix1) * NM), wx  * wy1 * s);
    atomicAdd(Wb + ((iy1 * NH + ix0) * NM), wx1 * wy  * s);
    atomicAdd(Wb + ((iy1 * NH + ix1) * NM), wx  * wy  * s);
}

// ---- Phase 2: P[kc][b][m][c] = sum_{hw in chunk kc} W[b][hw][m]*F[b][hw][c]
// 512 blocks. W chunk (32 KB) staged in LDS, broadcast b128 reads.
// F loads prefetched 8 deep in registers to cover HBM latency.
__global__ __launch_bounds__(256, 2) void wgemm(
    const float* __restrict__ W, const float* __restrict__ F,
    float* __restrict__ P)
{
    __shared__ float4 sW[KC * NM / 4];          // 2048 float4 = 32 KB

    const int kc  = blockIdx.x;                 // 16 k-chunks
    const int ct  = blockIdx.y;                 // 4 c-tiles
    const int b   = blockIdx.z;
    const int tid = threadIdx.x;
    const int c   = ct * CT + tid;
    const int hw0 = kc * KC;

    // stage W[hw0:hw0+KC][0:32] -> LDS (8192 floats, 8 float4/thread)
    const float4* Wg = (const float4*)(W + ((size_t)b * NHW + hw0) * NM);
#pragma unroll
    for (int j = 0; j < 8; ++j)
        sW[tid + 256 * j] = Wg[tid + 256 * j];
    __syncthreads();

    const float* Fb = F + ((size_t)b * NHW + hw0) * NC + c;

    float acc[NM];
#pragma unroll
    for (int m = 0; m < NM; ++m) acc[m] = 0.0f;

    float fbuf[PF];
#pragma unroll
    for (int j = 0; j < PF; ++j) fbuf[j] = Fb[(size_t)j * NC];

    for (int i = 0; i < KC; i += PF) {
        float fcur[PF];
#pragma unroll
        for (int j = 0; j < PF; ++j) fcur[j] = fbuf[j];
        if (i + PF < KC) {
#pragma unroll
            for (int j = 0; j < PF; ++j)
                fbuf[j] = Fb[(size_t)(i + PF + j) * NC];
        }
#pragma unroll
        for (int j = 0; j < PF; ++j) {
            const float4* w4 = sW + (i + j) * (NM / 4);
            float f = fcur[j];
#pragma unroll
            for (int mq = 0; mq < NM / 4; ++mq) {
                float4 w = w4[mq];
                acc[mq * 4 + 0] = fmaf(w.x, f, acc[mq * 4 + 0]);
                acc[mq * 4 + 1] = fmaf(w.y, f, acc[mq * 4 + 1]);
                acc[mq * 4 + 2] = fmaf(w.z, f, acc[mq * 4 + 2]);
                acc[mq * 4 + 3] = fmaf(w.w, f, acc[mq * 4 + 3]);
            }
        }
    }

    // partials: P[((kc*NB + b)*NM + m)*NC + c]
    float* pb = P + (((size_t)kc * NB + b) * NM) * NC + c;
#pragma unroll
    for (int m = 0; m < NM; ++m)
        pb[(size_t)m * NC] = acc[m];
}

// ---- Phase 3: out = sum over the 16 k-chunk partials ----
__global__ __launch_bounds__(256) void reduce_p(
    const float* __restrict__ P, float* __restrict__ out)
{
    const int idx = blockIdx.x * 256 + threadIdx.x;   // [0, NB*NM*NC/4)
    const float4* p4 = (const float4*)P;
    const int stride = NB * NM * NC / 4;              // 65536
    float4 s = make_float4(0.f, 0.f, 0.f, 0.f);
#pragma unroll
    for (int kc = 0; kc < NKC; ++kc) {
        float4 v = p4[(size_t)kc * stride + idx];
        s.x += v.x; s.y += v.y; s.z += v.z; s.w += v.w;
    }
    ((float4*)out)[idx] = s;
}

// ---- Fallback (ws too small): direct gather ----
__global__ __launch_bounds__(256) void region_pool_direct(
    const float* __restrict__ fm, const float* __restrict__ pc,
    float* __restrict__ out)
{
    __shared__ int4   sIdx[NP];
    __shared__ float4 sWt[NP];
    const int bid = blockIdx.x;
    const int b   = bid >> 5;
    const int tid = threadIdx.x;
    const float2* pc2 = (const float2*)(pc + (size_t)bid * NP * 2);
    for (int p = tid; p < NP; p += 256) {
        float2 c = pc2[p];
        float y = c.x * 63.0f, x = c.y * 63.0f;
        float x0f = floorf(x), y0f = floorf(y);
        float wx = x - x0f, wy = y - y0f;
        int ix0 = min(max((int)x0f, 0), 63);
        int ix1 = min(ix0 + 1, 63);
        int iy0 = min(max((int)y0f, 0), 63);
        int iy1 = min(iy0 + 1, 63);
        sIdx[p] = make_int4((iy0 * NH + ix0) << 10, (iy0 * NH + ix1) << 10,
                            (iy1 * NH + ix0) << 10, (iy1 * NH + ix1) << 10);
        float wx1 = 1.0f - wx, wy1 = 1.0f - wy;
        sWt[p] = make_float4(wx1 * wy1, wx * wy1, wx1 * wy, wx * wy);
    }
    __syncthreads();
    const float* Fb = fm + (size_t)b * (NHW * NC) + tid * 4;
    float4 acc = make_float4(0.f, 0.f, 0.f, 0.f);
#pragma unroll 4
    for (int p = 0; p < NP; ++p) {
        int4 off = sIdx[p]; float4 w = sWt[p];
        float4 f00 = *(const float4*)(Fb + off.x);
        float4 f01 = *(const float4*)(Fb + off.y);
        float4 f10 = *(const float4*)(Fb + off.z);
        float4 f11 = *(const float4*)(Fb + off.w);
        acc.x = fmaf(w.x, f00.x, fmaf(w.y, f01.x, fmaf(w.z, f10.x, fmaf(w.w, f11.x, acc.x))));
        acc.y = fmaf(w.x, f00.y, fmaf(w.y, f01.y, fmaf(w.z, f10.y, fmaf(w.w, f11.y, acc.y))));
        acc.z = fmaf(w.x, f00.z, fmaf(w.y, f01.z, fmaf(w.z, f10.z, fmaf(w.w, f11.z, acc.z))));
        acc.w = fmaf(w.x, f00.w, fmaf(w.y, f01.w, fmaf(w.z, f10.w, fmaf(w.w, f11.w, acc.w))));
    }
    const float inv = 1.0f / (float)NP;
    ((float4*)(out + (size_t)bid * NC))[tid] =
        make_float4(acc.x * inv, acc.y * inv, acc.z * inv, acc.w * inv);
}

extern "C" void kernel_launch(void* const* d_in, const int* in_sizes, int n_in,
                              void* d_out, int out_size, void* d_ws, size_t ws_size,
                              hipStream_t stream) {
    const float* fm = (const float*)d_in[0];   // [8, 4096, 1024]
    const float* pc = (const float*)d_in[1];   // [8, 32, 512, 2]
    float* out = (float*)d_out;                // [8, 32, 1, 1024]

    const size_t wbytes = (size_t)NB * NHW * NM * sizeof(float);           // 4 MB
    const size_t pbytes = (size_t)NKC * NB * NM * NC * sizeof(float);      // 16 MB
    if (ws_size >= wbytes + pbytes) {
        float* W = (float*)d_ws;
        float* P = (float*)((char*)d_ws + wbytes);
        hipMemsetAsync(W, 0, wbytes, stream);
        scatter_w<<<(NB * NM * NP) / 256, 256, 0, stream>>>(pc, W);
        dim3 grid(NKC, NCT, NB);
        wgemm<<<grid, CT, 0, stream>>>(W, fm, P);
        reduce_p<<<(NB * NM * NC / 4) / 256, 256, 0, stream>>>(P, out);
    } else {
        region_pool_direct<<<NB * NM, 256, 0, stream>>>(fm, pc, out);
    }
}